// Round 7
// baseline (312.326 us; speedup 1.0000x reference)
//
#include <hip/hip_runtime.h>
#include <math.h>

// Sizes (fixed by the problem)
#define BATCH 512   // scan sequence length (original batch dim)
#define E     128
#define DI    256
#define S     256
#define DTR   8
#define KCONV 4
#define JWX   520   // dt(8) + B(256) + C(256)

__device__ __forceinline__ float silu_f(float v) {
    return v / (1.0f + __expf(-v));
}

__device__ __forceinline__ float dot128(const float* __restrict__ w,
                                        const float* __restrict__ u) {
    const float4* wp = (const float4*)w;
    float a = 0.0f;
#pragma unroll 8
    for (int e4 = 0; e4 < 32; e4++) {
        const float4 ww = wp[e4];
        a += u[4*e4]*ww.x + u[4*e4+1]*ww.y + u[4*e4+2]*ww.z + u[4*e4+3]*ww.w;
    }
    return a;
}

// ===========================================================================
// k_front: 128 blocks, block g owns batch rows 4g..4g+3.
// conv2d+lin row31 for rows 4g-3..4g+3 (3 recomputed -> no cross-block dep),
// W_in projection -> xm (LDS only) + zg, causal conv1d+silu -> xs,
// W_x projection -> Bm/Cm/dtin, delta = softplus(dtin@W_dt.T + b_dt).
// Body identical to R5 P01 (verified absmax 1.8e-12).
// ===========================================================================
__global__ __launch_bounds__(256, 2) void k_front(
    const float* __restrict__ x, const float* __restrict__ conv_w,
    const float* __restrict__ conv_b, const float* __restrict__ lin_w,
    const float* __restrict__ lin_b, const float* __restrict__ W_in,
    const float* __restrict__ c1w, const float* __restrict__ conv1d_b,
    const float* __restrict__ W_x, const float* __restrict__ W_dt,
    const float* __restrict__ b_dt,
    float* __restrict__ zg, float* __restrict__ xs_g,
    float* __restrict__ delta_g, float* __restrict__ Bm,
    float* __restrict__ Cm)
{
    const int tid = threadIdx.x;
    const int wv = tid >> 6, ln = tid & 63;
    const int g = blockIdx.x, bb = g * 4;

    __shared__ float lw[1024];
    __shared__ float red[10][4];
    __shared__ float Tsh[10];
    __shared__ float ush[E];
    __shared__ float xml[7][DI];
    __shared__ float xs_sh[4][DI];
    __shared__ float dtin[4][8];

    const float4 lv = ((const float4*)(lin_w + 31 * 1024))[tid];
    ((float4*)lw)[tid] = lv;
    __syncthreads();

    for (int i = 0; i < 7; i++) {          // rows bb-3 .. bb+3
        const int b = bb - 3 + i;
        if (b < 0) continue;               // block-uniform

        float acc[10];
#pragma unroll
        for (int k = 0; k < 10; k++) acc[k] = 0.0f;

        const float4 xv = ((const float4*)(x + (size_t)b * 1024))[tid];
        const int p0 = tid * 4;
        const int h = p0 >> 5, w0 = p0 & 31;
        const float xa[4] = {xv.x, xv.y, xv.z, xv.w};
#pragma unroll
        for (int k = 0; k < 4; k++) {
            const float xval = xa[k];
            const int w = w0 + k;
#pragma unroll
            for (int ii = 0; ii < 3; ii++) {
                const int hh = h - (ii - 1);
                if (hh < 0 || hh > 31) continue;
#pragma unroll
                for (int j = 0; j < 3; j++) {
                    const int ww = w - (j - 1);
                    if (ww < 0 || ww > 31) continue;
                    acc[ii * 3 + j] += xval * lw[hh * 32 + ww];
                }
            }
        }
        acc[9] = lv.x + lv.y + lv.z + lv.w;   // partial sum of lin_w row

#pragma unroll
        for (int k = 0; k < 10; k++) {
#pragma unroll
            for (int m = 1; m < 64; m <<= 1) acc[k] += __shfl_xor(acc[k], m, 64);
        }
        if (ln == 0) {
#pragma unroll
            for (int k = 0; k < 10; k++) red[k][wv] = acc[k];
        }
        __syncthreads();
        if (tid < 10) Tsh[tid] = red[tid][0] + red[tid][1] + red[tid][2] + red[tid][3];
        __syncthreads();

        if (tid < E) {
            const int e = tid;
            float val = lin_b[31] + conv_b[e] * Tsh[9];
#pragma unroll
            for (int k = 0; k < 9; k++) val += conv_w[e * 9 + k] * Tsh[k];
            ush[e] = val;
        }
        __syncthreads();

        xml[i][tid] = dot128(W_in + (size_t)tid * E, ush);
        if (i >= 3) zg[b * DI + tid] = dot128(W_in + (size_t)(tid + 256) * E, ush);
        __syncthreads();   // ush/Tsh/red reused next iteration
    }

    // conv1d (K=4, causal) + silu -> xs
    {
        const float4 wc = ((const float4*)c1w)[tid];
        const float cb = conv1d_b[tid];
#pragma unroll
        for (int r = 0; r < 4; r++) {
            const int b = bb + r;
            float a = cb;
            if (b >= 3) a += xml[r + 0][tid] * wc.x;
            if (b >= 2) a += xml[r + 1][tid] * wc.y;
            if (b >= 1) a += xml[r + 2][tid] * wc.z;
            a += xml[r + 3][tid] * wc.w;
            const float s = silu_f(a);
            xs_sh[r][tid] = s;
            xs_g[b * DI + tid] = s;
        }
    }
    __syncthreads();

    // W_x projection (direct row reads)
    for (int jj = tid; jj < JWX; jj += 256) {
        const float4* wr = (const float4*)(W_x + (size_t)jj * DI);
        float a0 = 0.f, a1 = 0.f, a2 = 0.f, a3 = 0.f;
#pragma unroll 8
        for (int c4 = 0; c4 < 64; c4++) {
            const float4 w = wr[c4];
            a0 += xs_sh[0][4*c4]*w.x + xs_sh[0][4*c4+1]*w.y + xs_sh[0][4*c4+2]*w.z + xs_sh[0][4*c4+3]*w.w;
            a1 += xs_sh[1][4*c4]*w.x + xs_sh[1][4*c4+1]*w.y + xs_sh[1][4*c4+2]*w.z + xs_sh[1][4*c4+3]*w.w;
            a2 += xs_sh[2][4*c4]*w.x + xs_sh[2][4*c4+1]*w.y + xs_sh[2][4*c4+2]*w.z + xs_sh[2][4*c4+3]*w.w;
            a3 += xs_sh[3][4*c4]*w.x + xs_sh[3][4*c4+1]*w.y + xs_sh[3][4*c4+2]*w.z + xs_sh[3][4*c4+3]*w.w;
        }
        const float av[4] = {a0, a1, a2, a3};
#pragma unroll
        for (int r = 0; r < 4; r++) {
            const int b = bb + r;
            if (jj < DTR)          dtin[r][jj] = av[r];
            else if (jj < DTR + S) Bm[b * S + (jj - DTR)] = av[r];
            else                   Cm[b * S + (jj - DTR - S)] = av[r];
        }
    }
    __syncthreads();

    // delta = softplus(dtin @ W_dt.T + b_dt)
    {
        const int d = tid;
        const float bd = b_dt[d];
        const float4 wd0 = ((const float4*)(W_dt + d * DTR))[0];
        const float4 wd1 = ((const float4*)(W_dt + d * DTR))[1];
#pragma unroll
        for (int r2 = 0; r2 < 4; r2++) {
            float a = bd
                + dtin[r2][0]*wd0.x + dtin[r2][1]*wd0.y + dtin[r2][2]*wd0.z + dtin[r2][3]*wd0.w
                + dtin[r2][4]*wd1.x + dtin[r2][5]*wd1.y + dtin[r2][6]*wd1.z + dtin[r2][7]*wd1.w;
            delta_g[(bb + r2) * DI + d] = (a > 20.0f) ? a : log1pf(__expf(a));
        }
    }
}

// ===========================================================================
// k_scan: 256 blocks. Block idx: xp = idx&63 -> d-quad (d = xp*4+wv),
// q = idx>>6 -> s-quarter (s = q*64+ln). ONE serial pass t=0..511
// (exact reference recurrence order), 64-lane reduce -> ypart[q].
// Body identical to R6 SCAN (verified absmax 1.8e-12).
// ===========================================================================
__global__ __launch_bounds__(256, 2) void k_scan(
    const float* __restrict__ A_log, const float* __restrict__ delta_g,
    const float* __restrict__ xs_g, const float* __restrict__ Bm,
    const float* __restrict__ Cm, float* __restrict__ ypart)
{
    const int tid = threadIdx.x;
    const int wv = tid >> 6, ln = tid & 63;
    const int xp = blockIdx.x & 63;
    const int q  = blockIdx.x >> 6;
    const int d  = xp * 4 + wv;
    const int s  = q * 64 + ln;

    const float A = -__expf(A_log[d * S + s]);
    float h = 0.0f;
    float* yp = ypart + ((size_t)q * BATCH) * DI + d;

    for (int tb = 0; tb < BATCH; tb += 8) {
        float pr[8];
#pragma unroll
        for (int i = 0; i < 8; i++) {
            const int tt = tb + i;
            const float dd = delta_g[tt * DI + d];
            const float u  = dd * xs_g[tt * DI + d];
            const float bv = Bm[tt * S + s];
            const float cv = Cm[tt * S + s];
            h = __expf(dd * A) * h + u * bv;
            pr[i] = h * cv;
        }
#pragma unroll
        for (int i = 0; i < 8; i++) {
#pragma unroll
            for (int m = 1; m < 64; m <<= 1) pr[i] += __shfl_xor(pr[i], m, 64);
        }
        if (ln == 0) {
#pragma unroll
            for (int i = 0; i < 8; i++) yp[(tb + i) * DI] = pr[i];
        }
    }
}

// ===========================================================================
// k_back: 128 blocks, 4 batch rows each. y = sum of 4 s-quarter partials;
// yf = (y + xs*Dp)*silu(zg); feat = yf @ W_out.T; 3 head matmuls -> out.
// Body identical to R6 HEADS (verified absmax 1.8e-12).
// ===========================================================================
__global__ __launch_bounds__(256, 2) void k_back(
    const float* __restrict__ ypart, const float* __restrict__ xs_g,
    const float* __restrict__ Dp, const float* __restrict__ zg,
    const float* __restrict__ W_out,
    const float* __restrict__ We, const float* __restrict__ be,
    const float* __restrict__ Wa, const float* __restrict__ ba,
    const float* __restrict__ Wq, const float* __restrict__ bq,
    float* __restrict__ out)
{
    const int tid = threadIdx.x;
    const int bb = blockIdx.x * 4;

    __shared__ float yf[4][DI];
    __shared__ float feat[4][E];

    for (int idx = tid; idx < 4 * DI; idx += 256) {
        const int r = idx >> 8, cc = idx & 255;
        const int b = bb + r;
        const float y0 = ypart[((size_t)0 * BATCH + b) * DI + cc];
        const float y1 = ypart[((size_t)1 * BATCH + b) * DI + cc];
        const float y2 = ypart[((size_t)2 * BATCH + b) * DI + cc];
        const float y3 = ypart[((size_t)3 * BATCH + b) * DI + cc];
        const float yv = (y0 + y1) + (y2 + y3);
        const float z = zg[b * DI + cc];
        yf[r][cc] = (yv + xs_g[b * DI + cc] * Dp[cc]) * silu_f(z);
    }
    __syncthreads();

    for (int it = 0; it < 2; it++) {
        const int r = (tid >> 7) + it * 2;
        const int e = tid & 127;
        const float4* wr = (const float4*)(W_out + (size_t)e * DI);
        float a = 0.0f;
#pragma unroll 8
        for (int d4 = 0; d4 < 64; d4++) {
            const float4 w = wr[d4];
            a += yf[r][4*d4]*w.x + yf[r][4*d4+1]*w.y + yf[r][4*d4+2]*w.z + yf[r][4*d4+3]*w.w;
        }
        feat[r][e] = a;
    }
    __syncthreads();

    if (tid < 32) {
        const int r = tid >> 3, hd = tid & 7;
        const int b = bb + r;
        const float* wrow;
        float bias;
        int dst;
        if (hd == 0)      { wrow = We;                 bias = be[0];      dst = b; }
        else if (hd < 4)  { wrow = Wa + (hd - 1) * E;  bias = ba[hd - 1]; dst = 512 + b * 3 + (hd - 1); }
        else              { wrow = Wq + (hd - 4) * E;  bias = bq[hd - 4]; dst = 2048 + b * 4 + (hd - 4); }
        float a = bias;
#pragma unroll 4
        for (int e = 0; e < E; e++) a += feat[r][e] * wrow[e];
        out[dst] = a;
    }
}

// ===========================================================================
extern "C" void kernel_launch(void* const* d_in, const int* in_sizes, int n_in,
                              void* d_out, int out_size, void* d_ws, size_t ws_size,
                              hipStream_t stream)
{
    const float* x        = (const float*)d_in[0];
    const float* conv_w   = (const float*)d_in[1];
    const float* conv_b   = (const float*)d_in[2];
    const float* lin_w    = (const float*)d_in[3];
    const float* lin_b    = (const float*)d_in[4];
    const float* W_in     = (const float*)d_in[5];
    const float* conv1d_w = (const float*)d_in[6];
    const float* conv1d_b = (const float*)d_in[7];
    const float* W_x      = (const float*)d_in[8];
    const float* W_dt     = (const float*)d_in[9];
    const float* b_dt     = (const float*)d_in[10];
    const float* A_log    = (const float*)d_in[11];
    const float* Dp       = (const float*)d_in[12];
    const float* W_out    = (const float*)d_in[13];
    const float* We       = (const float*)d_in[14];
    const float* be       = (const float*)d_in[15];
    const float* Wa       = (const float*)d_in[16];
    const float* ba       = (const float*)d_in[17];
    const float* Wq       = (const float*)d_in[18];
    const float* bq       = (const float*)d_in[19];
    float* out = (float*)d_out;

    float* ws = (float*)d_ws;
    float* zg     = ws;                          // 512*256 each
    float* xs     = zg    + 512 * 256;
    float* delta  = xs    + 512 * 256;
    float* Bm     = delta + 512 * 256;
    float* Cm     = Bm    + 512 * 256;
    float* ypart  = Cm    + 512 * 256;           // 4 * 512*256

    k_front<<<128, 256, 0, stream>>>(x, conv_w, conv_b, lin_w, lin_b, W_in,
                                     conv1d_w, conv1d_b, W_x, W_dt, b_dt,
                                     zg, xs, delta, Bm, Cm);
    k_scan<<<256, 256, 0, stream>>>(A_log, delta, xs, Bm, Cm, ypart);
    k_back<<<128, 256, 0, stream>>>(ypart, xs, Dp, zg, W_out,
                                    We, be, Wa, ba, Wq, bq, out);
}

// Round 8
// 182.813 us; speedup vs baseline: 1.7084x; 1.7084x over previous
//
#include <hip/hip_runtime.h>
#include <math.h>

// Sizes (fixed by the problem)
#define BATCH 512   // scan sequence length (original batch dim)
#define E     128
#define DI    256
#define S     256
#define DTR   8
#define KCONV 4
#define JWX   520   // dt(8) + B(256) + C(256)
#define NC    32    // scan chunks
#define TCV   (BATCH / NC)

__device__ __forceinline__ float silu_f(float v) {
    return v / (1.0f + __expf(-v));
}

// ---------------------------------------------------------------------------
// kA: blocks 0..511  : conv2d+lin row-31 projection -> u (LDS) -> fused
//                      W_in projection -> xm, zg
//     blocks 512..522: W_x / W_out transposes (for coalesced k2b/k4 reads)
// (verified R1, absmax 3.6e-12)
// ---------------------------------------------------------------------------
__global__ __launch_bounds__(256) void kA_pre(
    const float* __restrict__ x, const float* __restrict__ conv_w,
    const float* __restrict__ conv_b, const float* __restrict__ lin_w,
    const float* __restrict__ lin_b, const float* __restrict__ W_in,
    const float* __restrict__ W_x, const float* __restrict__ W_out,
    float* __restrict__ xm, float* __restrict__ zg,
    float* __restrict__ W_xT, float* __restrict__ W_outT)
{
    const int tid = threadIdx.x;
    if (blockIdx.x >= 512) {
        const int bid = blockIdx.x - 512;
        const float* src; float* dst; int J, K, j0;
        if (bid < 9) { src = W_x;   dst = W_xT;   J = JWX; K = DI; j0 = bid * 64; }
        else         { src = W_out; dst = W_outT; J = E;   K = DI; j0 = (bid - 9) * 64; }
        const int j = j0 + (tid & 63);
        if (j >= J) return;
        for (int c = tid >> 6; c < K; c += 4)
            dst[c * J + j] = src[j * K + c];
        return;
    }

    const int b = blockIdx.x;
    __shared__ float lw[1024];
    __shared__ float red[10][4];
    __shared__ float Tsh[10];
    __shared__ float u[E];

    const float4 lv = ((const float4*)(lin_w + 31 * 1024))[tid];
    ((float4*)lw)[tid] = lv;
    __syncthreads();

    float acc[10];
#pragma unroll
    for (int k = 0; k < 10; k++) acc[k] = 0.0f;

    const float4 xv = ((const float4*)(x + (size_t)b * 1024))[tid];
    const int p0 = tid * 4;
    const int h = p0 >> 5, w0 = p0 & 31;
    const float xa[4] = {xv.x, xv.y, xv.z, xv.w};
#pragma unroll
    for (int k = 0; k < 4; k++) {
        const float xval = xa[k];
        const int w = w0 + k;
#pragma unroll
        for (int i = 0; i < 3; i++) {
            const int hh = h - (i - 1);
            if (hh < 0 || hh > 31) continue;
#pragma unroll
            for (int j = 0; j < 3; j++) {
                const int ww = w - (j - 1);
                if (ww < 0 || ww > 31) continue;
                acc[i * 3 + j] += xval * lw[hh * 32 + ww];
            }
        }
    }
    acc[9] = lv.x + lv.y + lv.z + lv.w;

    const int wv = tid >> 6, ln = tid & 63;
#pragma unroll
    for (int k = 0; k < 10; k++) {
#pragma unroll
        for (int m = 1; m < 64; m <<= 1) acc[k] += __shfl_xor(acc[k], m, 64);
    }
    if (ln == 0) {
#pragma unroll
        for (int k = 0; k < 10; k++) red[k][wv] = acc[k];
    }
    __syncthreads();
    if (tid < 10) Tsh[tid] = red[tid][0] + red[tid][1] + red[tid][2] + red[tid][3];
    __syncthreads();

    if (tid < E) {
        const int e = tid;
        float v = lin_b[31] + conv_b[e] * Tsh[9];
#pragma unroll
        for (int k = 0; k < 9; k++) v += conv_w[e * 9 + k] * Tsh[k];
        u[e] = v;
    }
    __syncthreads();

    {
        const float4* w0p = (const float4*)(W_in + (size_t)tid * E);
        const float4* w1p = (const float4*)(W_in + (size_t)(tid + 256) * E);
        float a0 = 0.0f;
#pragma unroll 8
        for (int e4 = 0; e4 < E / 4; e4++) {
            const float4 w = w0p[e4];
            a0 += u[4*e4]*w.x + u[4*e4+1]*w.y + u[4*e4+2]*w.z + u[4*e4+3]*w.w;
        }
        float a1 = 0.0f;
#pragma unroll 8
        for (int e4 = 0; e4 < E / 4; e4++) {
            const float4 w = w1p[e4];
            a1 += u[4*e4]*w.x + u[4*e4+1]*w.y + u[4*e4+2]*w.z + u[4*e4+3]*w.w;
        }
        xm[b * DI + tid] = a0;
        zg[b * DI + tid] = a1;
    }
}

// ---------------------------------------------------------------------------
// K2b: causal depthwise conv1d(K=4)+silu -> xs; dbl = xs @ W_x.T (via W_xT);
//      delta = softplus(...); Bm/Cm split. (verified R1)
// ---------------------------------------------------------------------------
__global__ __launch_bounds__(256) void k2b_conv_wx(
    const float* __restrict__ xm, const float* __restrict__ c1w,
    const float* __restrict__ conv1d_b, const float* __restrict__ W_xT,
    const float* __restrict__ W_dt, const float* __restrict__ b_dt,
    float* __restrict__ xs_g, float* __restrict__ delta_g,
    float* __restrict__ Bm, float* __restrict__ Cm)
{
    const int bb = blockIdx.x * 4;
    const int g = blockIdx.y;
    const int tid = threadIdx.x;
    __shared__ float xs[4][DI];
    __shared__ float dtin[4][8];

    for (int idx = tid; idx < 4 * DI; idx += 256) {
        const int r = idx >> 8, c = idx & 255;
        const int b = bb + r;
        const float4 wc = ((const float4*)c1w)[c];
        float a = conv1d_b[c];
        if (b >= 3) a += xm[(b - 3) * DI + c] * wc.x;
        if (b >= 2) a += xm[(b - 2) * DI + c] * wc.y;
        if (b >= 1) a += xm[(b - 1) * DI + c] * wc.z;
        a += xm[b * DI + c] * wc.w;
        const float s = silu_f(a);
        xs[r][c] = s;
        if (g == 0) xs_g[b * DI + c] = s;
    }
    __syncthreads();

    const int r = tid >> 6;
    const int j = g * 64 + (tid & 63);
    if (j < JWX) {
        float a = 0.0f;
#pragma unroll 8
        for (int c = 0; c < DI; c++) a += xs[r][c] * W_xT[c * JWX + j];
        const int b = bb + r;
        if (j < DTR)          dtin[r][j] = a;
        else if (j < DTR + S) Bm[b * S + (j - DTR)] = a;
        else                  Cm[b * S + (j - DTR - S)] = a;
    }
    __syncthreads();

    if (g == 0) {
        const int d = tid;
        const float bd = b_dt[d];
        const float4 wd0 = ((const float4*)(W_dt + d * DTR))[0];
        const float4 wd1 = ((const float4*)(W_dt + d * DTR))[1];
#pragma unroll
        for (int r2 = 0; r2 < 4; r2++) {
            float a = bd
                + dtin[r2][0]*wd0.x + dtin[r2][1]*wd0.y + dtin[r2][2]*wd0.z + dtin[r2][3]*wd0.w
                + dtin[r2][4]*wd1.x + dtin[r2][5]*wd1.y + dtin[r2][6]*wd1.z + dtin[r2][7]*wd1.w;
            const float sp = (a > 20.0f) ? a : log1pf(__expf(a));
            delta_g[(bb + r2) * DI + d] = sp;
        }
    }
}

// ---------------------------------------------------------------------------
// K3 chunked scan (NC=32): up-sweep produces hloc/Dchunk (no reductions,
// no y traffic). Down-sweep composes carry (Horner) + full recurrence -> y.
// 2048 blocks each => 8 blocks/CU => full latency hiding. (verified R1)
// ---------------------------------------------------------------------------
__global__ __launch_bounds__(256) void k3u_up(
    const float* __restrict__ A_log, const float* __restrict__ delta,
    const float* __restrict__ xs, const float* __restrict__ Bm,
    float* __restrict__ hloc, float* __restrict__ Dchunk)
{
    const int tid = threadIdx.x;
    const int wv = tid >> 6, ln = tid & 63;
    const int d = blockIdx.x * 4 + wv;
    const int c = blockIdx.y;
    const int s0 = ln * 4;
    const int t0 = c * TCV;

    const float4 al = *(const float4*)(A_log + d * S + s0);
    float4 A;
    A.x = -__expf(al.x); A.y = -__expf(al.y);
    A.z = -__expf(al.z); A.w = -__expf(al.w);

    float4 h = make_float4(0.f, 0.f, 0.f, 0.f);
    float cd = 0.0f;
    for (int tb = 0; tb < TCV; tb += 8) {
#pragma unroll
        for (int i = 0; i < 8; i++) {
            const int tt = t0 + tb + i;
            const float dd = delta[tt * DI + d];
            cd += dd;
            const float u = dd * xs[tt * DI + d];
            const float4 B = *(const float4*)(Bm + tt * S + s0);
            h.x = __expf(dd * A.x) * h.x + u * B.x;
            h.y = __expf(dd * A.y) * h.y + u * B.y;
            h.z = __expf(dd * A.z) * h.z + u * B.z;
            h.w = __expf(dd * A.w) * h.w + u * B.w;
        }
    }
    *(float4*)(hloc + ((size_t)(c * DI + d)) * S + s0) = h;
    if (ln == 0) Dchunk[c * DI + d] = cd;
}

__global__ __launch_bounds__(256) void k3d_down(
    const float* __restrict__ A_log, const float* __restrict__ delta,
    const float* __restrict__ xs, const float* __restrict__ Bm,
    const float* __restrict__ Cm, const float* __restrict__ hloc,
    const float* __restrict__ Dchunk, float* __restrict__ y)
{
    const int tid = threadIdx.x;
    const int wv = tid >> 6, ln = tid & 63;
    const int d = blockIdx.x * 4 + wv;
    const int c = (NC - 1) - blockIdx.y;   // heavy carries first
    const int s0 = ln * 4;
    const int t0 = c * TCV;

    const float4 al = *(const float4*)(A_log + d * S + s0);
    float4 A;
    A.x = -__expf(al.x); A.y = -__expf(al.y);
    A.z = -__expf(al.z); A.w = -__expf(al.w);

    // carry: h_in[c] via serial recurrence over chunk summaries
    float4 h = make_float4(0.f, 0.f, 0.f, 0.f);
    for (int cp = 1; cp <= c; cp++) {
        const float4 hl = *(const float4*)(hloc + ((size_t)((cp - 1) * DI + d)) * S + s0);
        const float Dc = Dchunk[(cp - 1) * DI + d];
        h.x = hl.x + __expf(A.x * Dc) * h.x;
        h.y = hl.y + __expf(A.y * Dc) * h.y;
        h.z = hl.z + __expf(A.z * Dc) * h.z;
        h.w = hl.w + __expf(A.w * Dc) * h.w;
    }

    float pr[8];
    for (int tb = 0; tb < TCV; tb += 8) {
#pragma unroll
        for (int i = 0; i < 8; i++) {
            const int tt = t0 + tb + i;
            const float dd = delta[tt * DI + d];
            const float u = dd * xs[tt * DI + d];
            const float4 B = *(const float4*)(Bm + tt * S + s0);
            const float4 C = *(const float4*)(Cm + tt * S + s0);
            h.x = __expf(dd * A.x) * h.x + u * B.x;
            h.y = __expf(dd * A.y) * h.y + u * B.y;
            h.z = __expf(dd * A.z) * h.z + u * B.z;
            h.w = __expf(dd * A.w) * h.w + u * B.w;
            pr[i] = h.x * C.x + h.y * C.y + h.z * C.z + h.w * C.w;
        }

        // multi-value butterfly reduce: 8 values in 10 shuffles (vs 48).
        // After stage 3, lane l holds value (l&7) summed over its 8-lane
        // group; stages 4-6 are plain butterflies. Lane l ends with the
        // 64-lane total of pr[l&7]; lanes 0..7 store directly.
        float q0, q1, q2, q3;
        {
            const bool b0 = (ln & 1);
            float s_, r_;
            s_ = b0 ? pr[0] : pr[1]; r_ = __shfl_xor(s_, 1, 64);
            q0 = (b0 ? pr[1] : pr[0]) + r_;
            s_ = b0 ? pr[2] : pr[3]; r_ = __shfl_xor(s_, 1, 64);
            q1 = (b0 ? pr[3] : pr[2]) + r_;
            s_ = b0 ? pr[4] : pr[5]; r_ = __shfl_xor(s_, 1, 64);
            q2 = (b0 ? pr[5] : pr[4]) + r_;
            s_ = b0 ? pr[6] : pr[7]; r_ = __shfl_xor(s_, 1, 64);
            q3 = (b0 ? pr[7] : pr[6]) + r_;
        }
        {
            const bool b1 = (ln & 2);
            float s_, r_;
            s_ = b1 ? q0 : q1; r_ = __shfl_xor(s_, 2, 64);
            q0 = (b1 ? q1 : q0) + r_;
            s_ = b1 ? q2 : q3; r_ = __shfl_xor(s_, 2, 64);
            q1 = (b1 ? q3 : q2) + r_;
        }
        {
            const bool b2 = (ln & 4);
            const float s_ = b2 ? q0 : q1;
            const float r_ = __shfl_xor(s_, 4, 64);
            q0 = (b2 ? q1 : q0) + r_;
        }
        q0 += __shfl_xor(q0, 8, 64);
        q0 += __shfl_xor(q0, 16, 64);
        q0 += __shfl_xor(q0, 32, 64);
        if (ln < 8) y[(t0 + tb + ln) * DI + d] = q0;
    }
}

// ---------------------------------------------------------------------------
// K4: yf = (y + xs*Dp)*silu(zg); feat = yf @ W_outT; 3 head matmuls -> out.
// (verified R1)
// ---------------------------------------------------------------------------
__global__ __launch_bounds__(256) void k4_heads(
    const float* __restrict__ y, const float* __restrict__ xs,
    const float* __restrict__ Dp, const float* __restrict__ zg,
    const float* __restrict__ W_outT,
    const float* __restrict__ We, const float* __restrict__ be,
    const float* __restrict__ Wa, const float* __restrict__ ba,
    const float* __restrict__ Wq, const float* __restrict__ bq,
    float* __restrict__ out)
{
    const int bb = blockIdx.x * 2;
    const int tid = threadIdx.x;
    __shared__ float yf[2][DI];
    __shared__ float feat[2][E];

    for (int idx = tid; idx < 2 * DI; idx += 256) {
        const int r = idx >> 8, c = idx & 255;
        const int b = bb + r;
        const float z = zg[b * DI + c];
        yf[r][c] = (y[b * DI + c] + xs[b * DI + c] * Dp[c]) * silu_f(z);
    }
    __syncthreads();

    {
        const int r = tid >> 7, e = tid & 127;
        float a = 0.0f;
#pragma unroll 8
        for (int dd = 0; dd < DI; dd++) a += yf[r][dd] * W_outT[dd * E + e];
        feat[r][e] = a;
    }
    __syncthreads();

    if (tid < 16) {
        const int r = tid >> 3, hd = tid & 7;
        const int b = bb + r;
        const float* wrow;
        float bias;
        int dst;
        if (hd == 0)      { wrow = We;                 bias = be[0];      dst = b; }
        else if (hd < 4)  { wrow = Wa + (hd - 1) * E;  bias = ba[hd - 1]; dst = 512 + b * 3 + (hd - 1); }
        else              { wrow = Wq + (hd - 4) * E;  bias = bq[hd - 4]; dst = 2048 + b * 4 + (hd - 4); }
        float a = bias;
#pragma unroll 4
        for (int e = 0; e < E; e++) a += feat[r][e] * wrow[e];
        out[dst] = a;
    }
}

// ===========================================================================
extern "C" void kernel_launch(void* const* d_in, const int* in_sizes, int n_in,
                              void* d_out, int out_size, void* d_ws, size_t ws_size,
                              hipStream_t stream)
{
    const float* x        = (const float*)d_in[0];
    const float* conv_w   = (const float*)d_in[1];
    const float* conv_b   = (const float*)d_in[2];
    const float* lin_w    = (const float*)d_in[3];
    const float* lin_b    = (const float*)d_in[4];
    const float* W_in     = (const float*)d_in[5];
    const float* conv1d_w = (const float*)d_in[6];
    const float* conv1d_b = (const float*)d_in[7];
    const float* W_x      = (const float*)d_in[8];
    const float* W_dt     = (const float*)d_in[9];
    const float* b_dt     = (const float*)d_in[10];
    const float* A_log    = (const float*)d_in[11];
    const float* Dp       = (const float*)d_in[12];
    const float* W_out    = (const float*)d_in[13];
    const float* We       = (const float*)d_in[14];
    const float* be       = (const float*)d_in[15];
    const float* Wa       = (const float*)d_in[16];
    const float* ba       = (const float*)d_in[17];
    const float* Wq       = (const float*)d_in[18];
    const float* bq       = (const float*)d_in[19];
    float* out = (float*)d_out;

    float* ws = (float*)d_ws;
    float* xm     = ws;                    // 512*256 each below
    float* zg     = xm     + 512 * 256;
    float* xs     = zg     + 512 * 256;
    float* delta  = xs     + 512 * 256;
    float* Bm     = delta  + 512 * 256;
    float* Cm     = Bm     + 512 * 256;
    float* y      = Cm     + 512 * 256;
    float* W_xT   = y      + 512 * 256;    // 256*520
    float* W_outT = W_xT   + 256 * JWX;    // 256*128
    float* hloc   = W_outT + 256 * 128;    // NC*DI*S
    float* Dchunk = hloc   + (size_t)NC * DI * S;   // NC*DI

    kA_pre<<<523, 256, 0, stream>>>(x, conv_w, conv_b, lin_w, lin_b,
                                    W_in, W_x, W_out, xm, zg, W_xT, W_outT);
    k2b_conv_wx<<<dim3(128, 9), 256, 0, stream>>>(xm, conv1d_w, conv1d_b, W_xT,
                                                  W_dt, b_dt, xs, delta, Bm, Cm);
    k3u_up<<<dim3(64, NC), 256, 0, stream>>>(A_log, delta, xs, Bm, hloc, Dchunk);
    k3d_down<<<dim3(64, NC), 256, 0, stream>>>(A_log, delta, xs, Bm, Cm,
                                               hloc, Dchunk, y);
    k4_heads<<<256, 256, 0, stream>>>(y, xs, Dp, zg, W_outT, We, be, Wa, ba, Wq, bq, out);
}

// Round 9
// 177.623 us; speedup vs baseline: 1.7584x; 1.0292x over previous
//
#include <hip/hip_runtime.h>
#include <math.h>

// Sizes (fixed by the problem)
#define BATCH 512   // scan sequence length (original batch dim)
#define E     128
#define DI    256
#define S     256
#define DTR   8
#define KCONV 4
#define JWX   520   // dt(8) + B(256) + C(256)
#define NC    32    // scan chunks
#define TCV   (BATCH / NC)

__device__ __forceinline__ float silu_f(float v) {
    return v / (1.0f + __expf(-v));
}

// ---------------------------------------------------------------------------
// kA: 512 blocks, block b: conv2d+lin row-31 projection -> u (LDS) -> fused
//     W_in projection -> xm, zg. Multi-value butterfly reduce (16 shuffles,
//     same summation tree as the 60-shuffle version -> bit-identical).
// ---------------------------------------------------------------------------
__global__ __launch_bounds__(256) void kA_pre(
    const float* __restrict__ x, const float* __restrict__ conv_w,
    const float* __restrict__ conv_b, const float* __restrict__ lin_w,
    const float* __restrict__ lin_b, const float* __restrict__ W_in,
    float* __restrict__ xm, float* __restrict__ zg)
{
    const int tid = threadIdx.x;
    const int b = blockIdx.x;
    __shared__ float lw[1024];
    __shared__ float red[10][4];
    __shared__ float Tsh[10];
    __shared__ float u[E];

    const float4 lv = ((const float4*)(lin_w + 31 * 1024))[tid];
    ((float4*)lw)[tid] = lv;
    __syncthreads();

    float acc[10];
#pragma unroll
    for (int k = 0; k < 10; k++) acc[k] = 0.0f;

    const float4 xv = ((const float4*)(x + (size_t)b * 1024))[tid];
    const int p0 = tid * 4;
    const int h = p0 >> 5, w0 = p0 & 31;
    const float xa[4] = {xv.x, xv.y, xv.z, xv.w};
#pragma unroll
    for (int k = 0; k < 4; k++) {
        const float xval = xa[k];
        const int w = w0 + k;
#pragma unroll
        for (int i = 0; i < 3; i++) {
            const int hh = h - (i - 1);
            if (hh < 0 || hh > 31) continue;
#pragma unroll
            for (int j = 0; j < 3; j++) {
                const int ww = w - (j - 1);
                if (ww < 0 || ww > 31) continue;
                acc[i * 3 + j] += xval * lw[hh * 32 + ww];
            }
        }
    }
    acc[9] = lv.x + lv.y + lv.z + lv.w;

    const int wv = tid >> 6, ln = tid & 63;

    // multi-value butterfly: values 0..7 land as R0 (lane&7 selects value);
    // values 8,9 as q4 (lane&1 selects). Same per-value summation tree as
    // the plain 6-stage butterfly -> bit-identical results.
    float R0, q4;
    {
        float q0, q1, q2, q3;
        {
            const bool b0 = (ln & 1);
            float s_, r_;
            s_ = b0 ? acc[0] : acc[1]; r_ = __shfl_xor(s_, 1, 64);
            q0 = (b0 ? acc[1] : acc[0]) + r_;
            s_ = b0 ? acc[2] : acc[3]; r_ = __shfl_xor(s_, 1, 64);
            q1 = (b0 ? acc[3] : acc[2]) + r_;
            s_ = b0 ? acc[4] : acc[5]; r_ = __shfl_xor(s_, 1, 64);
            q2 = (b0 ? acc[5] : acc[4]) + r_;
            s_ = b0 ? acc[6] : acc[7]; r_ = __shfl_xor(s_, 1, 64);
            q3 = (b0 ? acc[7] : acc[6]) + r_;
            s_ = b0 ? acc[8] : acc[9]; r_ = __shfl_xor(s_, 1, 64);
            q4 = (b0 ? acc[9] : acc[8]) + r_;
        }
        {
            const bool b1 = (ln & 2);
            float s_, r_;
            s_ = b1 ? q0 : q1; r_ = __shfl_xor(s_, 2, 64);
            q0 = (b1 ? q1 : q0) + r_;
            s_ = b1 ? q2 : q3; r_ = __shfl_xor(s_, 2, 64);
            q1 = (b1 ? q3 : q2) + r_;
            q4 += __shfl_xor(q4, 2, 64);
        }
        {
            const bool b2 = (ln & 4);
            const float s_ = b2 ? q0 : q1;
            const float r_ = __shfl_xor(s_, 4, 64);
            R0 = (b2 ? q1 : q0) + r_;
            q4 += __shfl_xor(q4, 4, 64);
        }
        R0 += __shfl_xor(R0, 8, 64);
        R0 += __shfl_xor(R0, 16, 64);
        R0 += __shfl_xor(R0, 32, 64);
        q4 += __shfl_xor(q4, 8, 64);
        q4 += __shfl_xor(q4, 16, 64);
        q4 += __shfl_xor(q4, 32, 64);
    }
    if (ln < 8) red[ln][wv] = R0;        // R0 on lane l = total of acc[l&7]
    if (ln < 2) red[8 + ln][wv] = q4;    // q4 on lane l = total of acc[8+(l&1)]
    __syncthreads();
    if (tid < 10) Tsh[tid] = red[tid][0] + red[tid][1] + red[tid][2] + red[tid][3];
    __syncthreads();

    if (tid < E) {
        const int e = tid;
        float v = lin_b[31] + conv_b[e] * Tsh[9];
#pragma unroll
        for (int k = 0; k < 9; k++) v += conv_w[e * 9 + k] * Tsh[k];
        u[e] = v;
    }
    __syncthreads();

    {
        const float4* w0p = (const float4*)(W_in + (size_t)tid * E);
        const float4* w1p = (const float4*)(W_in + (size_t)(tid + 256) * E);
        float a0 = 0.0f;
#pragma unroll 8
        for (int e4 = 0; e4 < E / 4; e4++) {
            const float4 w = w0p[e4];
            a0 += u[4*e4]*w.x + u[4*e4+1]*w.y + u[4*e4+2]*w.z + u[4*e4+3]*w.w;
        }
        float a1 = 0.0f;
#pragma unroll 8
        for (int e4 = 0; e4 < E / 4; e4++) {
            const float4 w = w1p[e4];
            a1 += u[4*e4]*w.x + u[4*e4+1]*w.y + u[4*e4+2]*w.z + u[4*e4+3]*w.w;
        }
        xm[b * DI + tid] = a0;
        zg[b * DI + tid] = a1;
    }
}

// ---------------------------------------------------------------------------
// K2b: grid (128, 4). gy = (jhalf<<1)|rpair-sel. Causal conv1d(K=4)+silu -> xs
// (all blocks recompute; gy==0 stores). Phase B: DIRECT W_x row float4 streams
// (64 dwordx4 per output-pair vs 256 scalar loads per output). Each thread:
// one j, two batch rows. Accumulation strictly c-ascending -> bit-identical.
// Phase C: delta for this block's 2 rows (jhalf==0 blocks own dtin).
// ---------------------------------------------------------------------------
__global__ __launch_bounds__(256) void k2b_conv_wx(
    const float* __restrict__ xm, const float* __restrict__ c1w,
    const float* __restrict__ conv1d_b, const float* __restrict__ W_x,
    const float* __restrict__ W_dt, const float* __restrict__ b_dt,
    float* __restrict__ xs_g, float* __restrict__ delta_g,
    float* __restrict__ Bm, float* __restrict__ Cm)
{
    const int bb = blockIdx.x * 4;
    const int gy = blockIdx.y;           // 0..3
    const int jhalf = gy >> 1;           // j range: [jhalf*260, jhalf*260+260)
    const int rp = (gy & 1) * 2;         // rows rp, rp+1
    const int tid = threadIdx.x;
    __shared__ float xs_sh[4][DI];
    __shared__ float dtin[2][8];

    // phase A: conv1d + silu (cheap; recomputed per gy, stored once)
    for (int idx = tid; idx < 4 * DI; idx += 256) {
        const int r = idx >> 8, c = idx & 255;
        const int b = bb + r;
        const float4 wc = ((const float4*)c1w)[c];
        float a = conv1d_b[c];
        if (b >= 3) a += xm[(b - 3) * DI + c] * wc.x;
        if (b >= 2) a += xm[(b - 2) * DI + c] * wc.y;
        if (b >= 1) a += xm[(b - 1) * DI + c] * wc.z;
        a += xm[b * DI + c] * wc.w;
        const float s = silu_f(a);
        xs_sh[r][c] = s;
        if (gy == 0) xs_g[b * DI + c] = s;
    }
    __syncthreads();

    // phase B: W_x rows streamed as float4; 2 rows per thread
    for (int jl = tid; jl < 260; jl += 256) {
        const int jj = jhalf * 260 + jl;             // < 520 always
        const float4* wr = (const float4*)(W_x + (size_t)jj * DI);
        const float4* xA = (const float4*)xs_sh[rp];
        const float4* xB = (const float4*)xs_sh[rp + 1];
        float a0 = 0.0f, a1 = 0.0f;
#pragma unroll 8
        for (int c4 = 0; c4 < 64; c4++) {
            const float4 w  = wr[c4];
            const float4 vA = xA[c4];
            const float4 vB = xB[c4];
            a0 += vA.x * w.x; a0 += vA.y * w.y; a0 += vA.z * w.z; a0 += vA.w * w.w;
            a1 += vB.x * w.x; a1 += vB.y * w.y; a1 += vB.z * w.z; a1 += vB.w * w.w;
        }
        const int b0 = bb + rp, b1 = bb + rp + 1;
        if (jj < DTR) {
            dtin[0][jj] = a0; dtin[1][jj] = a1;
        } else if (jj < DTR + S) {
            Bm[b0 * S + (jj - DTR)] = a0;
            Bm[b1 * S + (jj - DTR)] = a1;
        } else {
            Cm[b0 * S + (jj - DTR - S)] = a0;
            Cm[b1 * S + (jj - DTR - S)] = a1;
        }
    }
    __syncthreads();

    // phase C: delta = softplus(dtin @ W_dt.T + b_dt) for rows rp, rp+1
    if (jhalf == 0) {
        const int d = tid;
        const float bd = b_dt[d];
        const float4 wd0 = ((const float4*)(W_dt + d * DTR))[0];
        const float4 wd1 = ((const float4*)(W_dt + d * DTR))[1];
#pragma unroll
        for (int r2 = 0; r2 < 2; r2++) {
            float a = bd
                + dtin[r2][0]*wd0.x + dtin[r2][1]*wd0.y + dtin[r2][2]*wd0.z + dtin[r2][3]*wd0.w
                + dtin[r2][4]*wd1.x + dtin[r2][5]*wd1.y + dtin[r2][6]*wd1.z + dtin[r2][7]*wd1.w;
            const float sp = (a > 20.0f) ? a : log1pf(__expf(a));
            delta_g[(bb + rp + r2) * DI + d] = sp;
        }
    }
}

// ---------------------------------------------------------------------------
// K3 chunked scan (NC=32): unchanged from R8 (verified bit-identical).
// ---------------------------------------------------------------------------
__global__ __launch_bounds__(256) void k3u_up(
    const float* __restrict__ A_log, const float* __restrict__ delta,
    const float* __restrict__ xs, const float* __restrict__ Bm,
    float* __restrict__ hloc, float* __restrict__ Dchunk)
{
    const int tid = threadIdx.x;
    const int wv = tid >> 6, ln = tid & 63;
    const int d = blockIdx.x * 4 + wv;
    const int c = blockIdx.y;
    const int s0 = ln * 4;
    const int t0 = c * TCV;

    const float4 al = *(const float4*)(A_log + d * S + s0);
    float4 A;
    A.x = -__expf(al.x); A.y = -__expf(al.y);
    A.z = -__expf(al.z); A.w = -__expf(al.w);

    float4 h = make_float4(0.f, 0.f, 0.f, 0.f);
    float cd = 0.0f;
    for (int tb = 0; tb < TCV; tb += 8) {
#pragma unroll
        for (int i = 0; i < 8; i++) {
            const int tt = t0 + tb + i;
            const float dd = delta[tt * DI + d];
            cd += dd;
            const float u = dd * xs[tt * DI + d];
            const float4 B = *(const float4*)(Bm + tt * S + s0);
            h.x = __expf(dd * A.x) * h.x + u * B.x;
            h.y = __expf(dd * A.y) * h.y + u * B.y;
            h.z = __expf(dd * A.z) * h.z + u * B.z;
            h.w = __expf(dd * A.w) * h.w + u * B.w;
        }
    }
    *(float4*)(hloc + ((size_t)(c * DI + d)) * S + s0) = h;
    if (ln == 0) Dchunk[c * DI + d] = cd;
}

__global__ __launch_bounds__(256) void k3d_down(
    const float* __restrict__ A_log, const float* __restrict__ delta,
    const float* __restrict__ xs, const float* __restrict__ Bm,
    const float* __restrict__ Cm, const float* __restrict__ hloc,
    const float* __restrict__ Dchunk, float* __restrict__ y)
{
    const int tid = threadIdx.x;
    const int wv = tid >> 6, ln = tid & 63;
    const int d = blockIdx.x * 4 + wv;
    const int c = (NC - 1) - blockIdx.y;   // heavy carries first
    const int s0 = ln * 4;
    const int t0 = c * TCV;

    const float4 al = *(const float4*)(A_log + d * S + s0);
    float4 A;
    A.x = -__expf(al.x); A.y = -__expf(al.y);
    A.z = -__expf(al.z); A.w = -__expf(al.w);

    float4 h = make_float4(0.f, 0.f, 0.f, 0.f);
    for (int cp = 1; cp <= c; cp++) {
        const float4 hl = *(const float4*)(hloc + ((size_t)((cp - 1) * DI + d)) * S + s0);
        const float Dc = Dchunk[(cp - 1) * DI + d];
        h.x = hl.x + __expf(A.x * Dc) * h.x;
        h.y = hl.y + __expf(A.y * Dc) * h.y;
        h.z = hl.z + __expf(A.z * Dc) * h.z;
        h.w = hl.w + __expf(A.w * Dc) * h.w;
    }

    float pr[8];
    for (int tb = 0; tb < TCV; tb += 8) {
#pragma unroll
        for (int i = 0; i < 8; i++) {
            const int tt = t0 + tb + i;
            const float dd = delta[tt * DI + d];
            const float u = dd * xs[tt * DI + d];
            const float4 B = *(const float4*)(Bm + tt * S + s0);
            const float4 C = *(const float4*)(Cm + tt * S + s0);
            h.x = __expf(dd * A.x) * h.x + u * B.x;
            h.y = __expf(dd * A.y) * h.y + u * B.y;
            h.z = __expf(dd * A.z) * h.z + u * B.z;
            h.w = __expf(dd * A.w) * h.w + u * B.w;
            pr[i] = h.x * C.x + h.y * C.y + h.z * C.z + h.w * C.w;
        }

        float q0, q1, q2, q3;
        {
            const bool b0 = (ln & 1);
            float s_, r_;
            s_ = b0 ? pr[0] : pr[1]; r_ = __shfl_xor(s_, 1, 64);
            q0 = (b0 ? pr[1] : pr[0]) + r_;
            s_ = b0 ? pr[2] : pr[3]; r_ = __shfl_xor(s_, 1, 64);
            q1 = (b0 ? pr[3] : pr[2]) + r_;
            s_ = b0 ? pr[4] : pr[5]; r_ = __shfl_xor(s_, 1, 64);
            q2 = (b0 ? pr[5] : pr[4]) + r_;
            s_ = b0 ? pr[6] : pr[7]; r_ = __shfl_xor(s_, 1, 64);
            q3 = (b0 ? pr[7] : pr[6]) + r_;
        }
        {
            const bool b1 = (ln & 2);
            float s_, r_;
            s_ = b1 ? q0 : q1; r_ = __shfl_xor(s_, 2, 64);
            q0 = (b1 ? q1 : q0) + r_;
            s_ = b1 ? q2 : q3; r_ = __shfl_xor(s_, 2, 64);
            q1 = (b1 ? q3 : q2) + r_;
        }
        {
            const bool b2 = (ln & 4);
            const float s_ = b2 ? q0 : q1;
            const float r_ = __shfl_xor(s_, 4, 64);
            q0 = (b2 ? q1 : q0) + r_;
        }
        q0 += __shfl_xor(q0, 8, 64);
        q0 += __shfl_xor(q0, 16, 64);
        q0 += __shfl_xor(q0, 32, 64);
        if (ln < 8) y[(t0 + tb + ln) * DI + d] = q0;
    }
}

// ---------------------------------------------------------------------------
// K4: yf = (y + xs*Dp)*silu(zg); feat = yf @ W_out.T via direct float4 row
// streams (64 dwordx4 vs 256 scalar loads); 3 head matmuls -> out.
// ---------------------------------------------------------------------------
__global__ __launch_bounds__(256) void k4_heads(
    const float* __restrict__ y, const float* __restrict__ xs,
    const float* __restrict__ Dp, const float* __restrict__ zg,
    const float* __restrict__ W_out,
    const float* __restrict__ We, const float* __restrict__ be,
    const float* __restrict__ Wa, const float* __restrict__ ba,
    const float* __restrict__ Wq, const float* __restrict__ bq,
    float* __restrict__ out)
{
    const int bb = blockIdx.x * 2;
    const int tid = threadIdx.x;
    __shared__ float yf[2][DI];
    __shared__ float feat[2][E];

    for (int idx = tid; idx < 2 * DI; idx += 256) {
        const int r = idx >> 8, c = idx & 255;
        const int b = bb + r;
        const float z = zg[b * DI + c];
        yf[r][c] = (y[b * DI + c] + xs[b * DI + c] * Dp[c]) * silu_f(z);
    }
    __syncthreads();

    {
        const int r = tid >> 7, e = tid & 127;
        const float4* wr = (const float4*)(W_out + (size_t)e * DI);
        const float4* yv = (const float4*)yf[r];
        float a = 0.0f;
#pragma unroll 8
        for (int d4 = 0; d4 < 64; d4++) {
            const float4 w = wr[d4];
            const float4 v = yv[d4];
            a += v.x * w.x; a += v.y * w.y; a += v.z * w.z; a += v.w * w.w;
        }
        feat[r][e] = a;
    }
    __syncthreads();

    if (tid < 16) {
        const int r = tid >> 3, hd = tid & 7;
        const int b = bb + r;
        const float* wrow;
        float bias;
        int dst;
        if (hd == 0)      { wrow = We;                 bias = be[0];      dst = b; }
        else if (hd < 4)  { wrow = Wa + (hd - 1) * E;  bias = ba[hd - 1]; dst = 512 + b * 3 + (hd - 1); }
        else              { wrow = Wq + (hd - 4) * E;  bias = bq[hd - 4]; dst = 2048 + b * 4 + (hd - 4); }
        float a = bias;
#pragma unroll 4
        for (int e = 0; e < E; e++) a += feat[r][e] * wrow[e];
        out[dst] = a;
    }
}

// ===========================================================================
extern "C" void kernel_launch(void* const* d_in, const int* in_sizes, int n_in,
                              void* d_out, int out_size, void* d_ws, size_t ws_size,
                              hipStream_t stream)
{
    const float* x        = (const float*)d_in[0];
    const float* conv_w   = (const float*)d_in[1];
    const float* conv_b   = (const float*)d_in[2];
    const float* lin_w    = (const float*)d_in[3];
    const float* lin_b    = (const float*)d_in[4];
    const float* W_in     = (const float*)d_in[5];
    const float* conv1d_w = (const float*)d_in[6];
    const float* conv1d_b = (const float*)d_in[7];
    const float* W_x      = (const float*)d_in[8];
    const float* W_dt     = (const float*)d_in[9];
    const float* b_dt     = (const float*)d_in[10];
    const float* A_log    = (const float*)d_in[11];
    const float* Dp       = (const float*)d_in[12];
    const float* W_out    = (const float*)d_in[13];
    const float* We       = (const float*)d_in[14];
    const float* be       = (const float*)d_in[15];
    const float* Wa       = (const float*)d_in[16];
    const float* ba       = (const float*)d_in[17];
    const float* Wq       = (const float*)d_in[18];
    const float* bq       = (const float*)d_in[19];
    float* out = (float*)d_out;

    float* ws = (float*)d_ws;
    float* xm     = ws;                    // 512*256 each below
    float* zg     = xm     + 512 * 256;
    float* xs     = zg     + 512 * 256;
    float* delta  = xs     + 512 * 256;
    float* Bm     = delta  + 512 * 256;
    float* Cm     = Bm     + 512 * 256;
    float* y      = Cm     + 512 * 256;
    float* hloc   = y      + 512 * 256;    // NC*DI*S
    float* Dchunk = hloc   + (size_t)NC * DI * S;   // NC*DI

    kA_pre<<<512, 256, 0, stream>>>(x, conv_w, conv_b, lin_w, lin_b, W_in,
                                    xm, zg);
    k2b_conv_wx<<<dim3(128, 4), 256, 0, stream>>>(xm, conv1d_w, conv1d_b, W_x,
                                                  W_dt, b_dt, xs, delta, Bm, Cm);
    k3u_up<<<dim3(64, NC), 256, 0, stream>>>(A_log, delta, xs, Bm, hloc, Dchunk);
    k3d_down<<<dim3(64, NC), 256, 0, stream>>>(A_log, delta, xs, Bm, Cm,
                                               hloc, Dchunk, y);
    k4_heads<<<256, 256, 0, stream>>>(y, xs, Dp, zg, W_out, We, be, Wa, ba, Wq, bq, out);
}

// Round 10
// 174.208 us; speedup vs baseline: 1.7928x; 1.0196x over previous
//
#include <hip/hip_runtime.h>
#include <math.h>

// Sizes (fixed by the problem)
#define BATCH 512   // scan sequence length (original batch dim)
#define E     128
#define DI    256
#define S     256
#define DTR   8
#define KCONV 4
#define JWX   520   // dt(8) + B(256) + C(256)
#define NC    32    // scan chunks
#define TCV   (BATCH / NC)

__device__ __forceinline__ float silu_f(float v) {
    return v / (1.0f + __expf(-v));
}

// ---------------------------------------------------------------------------
// kA: 256 blocks, 2 batch rows each. conv2d+lin row-31 (multi-value butterfly,
// bit-identical tree) -> u0/u1; W_in projection with each loaded float4
// feeding BOTH rows (halves W_in L2 traffic, 2 FMA/float).
// ---------------------------------------------------------------------------
__global__ __launch_bounds__(256) void kA_pre(
    const float* __restrict__ x, const float* __restrict__ conv_w,
    const float* __restrict__ conv_b, const float* __restrict__ lin_w,
    const float* __restrict__ lin_b, const float* __restrict__ W_in,
    float* __restrict__ xm, float* __restrict__ zg)
{
    const int tid = threadIdx.x;
    const int bb = blockIdx.x * 2;
    __shared__ float lw[1024];
    __shared__ float red[10][4];
    __shared__ float Tsh[10];
    __shared__ float u0[E];
    __shared__ float u1[E];

    const float4 lv = ((const float4*)(lin_w + 31 * 1024))[tid];
    ((float4*)lw)[tid] = lv;
    __syncthreads();

    const int wv = tid >> 6, ln = tid & 63;

    for (int r = 0; r < 2; r++) {
        const int b = bb + r;

        float acc[10];
#pragma unroll
        for (int k = 0; k < 10; k++) acc[k] = 0.0f;

        const float4 xv = ((const float4*)(x + (size_t)b * 1024))[tid];
        const int p0 = tid * 4;
        const int h = p0 >> 5, w0 = p0 & 31;
        const float xa[4] = {xv.x, xv.y, xv.z, xv.w};
#pragma unroll
        for (int k = 0; k < 4; k++) {
            const float xval = xa[k];
            const int w = w0 + k;
#pragma unroll
            for (int i = 0; i < 3; i++) {
                const int hh = h - (i - 1);
                if (hh < 0 || hh > 31) continue;
#pragma unroll
                for (int j = 0; j < 3; j++) {
                    const int ww = w - (j - 1);
                    if (ww < 0 || ww > 31) continue;
                    acc[i * 3 + j] += xval * lw[hh * 32 + ww];
                }
            }
        }
        acc[9] = lv.x + lv.y + lv.z + lv.w;

        // multi-value butterfly (same per-value summation tree -> bit-identical)
        float R0, q4;
        {
            float q0, q1, q2, q3;
            {
                const bool b0 = (ln & 1);
                float s_, r_;
                s_ = b0 ? acc[0] : acc[1]; r_ = __shfl_xor(s_, 1, 64);
                q0 = (b0 ? acc[1] : acc[0]) + r_;
                s_ = b0 ? acc[2] : acc[3]; r_ = __shfl_xor(s_, 1, 64);
                q1 = (b0 ? acc[3] : acc[2]) + r_;
                s_ = b0 ? acc[4] : acc[5]; r_ = __shfl_xor(s_, 1, 64);
                q2 = (b0 ? acc[5] : acc[4]) + r_;
                s_ = b0 ? acc[6] : acc[7]; r_ = __shfl_xor(s_, 1, 64);
                q3 = (b0 ? acc[7] : acc[6]) + r_;
                s_ = b0 ? acc[8] : acc[9]; r_ = __shfl_xor(s_, 1, 64);
                q4 = (b0 ? acc[9] : acc[8]) + r_;
            }
            {
                const bool b1 = (ln & 2);
                float s_, r_;
                s_ = b1 ? q0 : q1; r_ = __shfl_xor(s_, 2, 64);
                q0 = (b1 ? q1 : q0) + r_;
                s_ = b1 ? q2 : q3; r_ = __shfl_xor(s_, 2, 64);
                q1 = (b1 ? q3 : q2) + r_;
                q4 += __shfl_xor(q4, 2, 64);
            }
            {
                const bool b2 = (ln & 4);
                const float s_ = b2 ? q0 : q1;
                const float r_ = __shfl_xor(s_, 4, 64);
                R0 = (b2 ? q1 : q0) + r_;
                q4 += __shfl_xor(q4, 4, 64);
            }
            R0 += __shfl_xor(R0, 8, 64);
            R0 += __shfl_xor(R0, 16, 64);
            R0 += __shfl_xor(R0, 32, 64);
            q4 += __shfl_xor(q4, 8, 64);
            q4 += __shfl_xor(q4, 16, 64);
            q4 += __shfl_xor(q4, 32, 64);
        }
        if (ln < 8) red[ln][wv] = R0;
        if (ln < 2) red[8 + ln][wv] = q4;
        __syncthreads();
        if (tid < 10) Tsh[tid] = red[tid][0] + red[tid][1] + red[tid][2] + red[tid][3];
        __syncthreads();

        if (tid < E) {
            const int e = tid;
            float v = lin_b[31] + conv_b[e] * Tsh[9];
#pragma unroll
            for (int k = 0; k < 9; k++) v += conv_w[e * 9 + k] * Tsh[k];
            if (r == 0) u0[e] = v; else u1[e] = v;
        }
        __syncthreads();
    }

    // W_in projection: each float4 of W_in feeds both rows (2 FMA/float)
    {
        const float4* w0p = (const float4*)(W_in + (size_t)tid * E);
        const float4* w1p = (const float4*)(W_in + (size_t)(tid + 256) * E);
        float a00 = 0.0f, a01 = 0.0f;
#pragma unroll 8
        for (int e4 = 0; e4 < E / 4; e4++) {
            const float4 w = w0p[e4];
            a00 += u0[4*e4]*w.x + u0[4*e4+1]*w.y + u0[4*e4+2]*w.z + u0[4*e4+3]*w.w;
            a01 += u1[4*e4]*w.x + u1[4*e4+1]*w.y + u1[4*e4+2]*w.z + u1[4*e4+3]*w.w;
        }
        float a10 = 0.0f, a11 = 0.0f;
#pragma unroll 8
        for (int e4 = 0; e4 < E / 4; e4++) {
            const float4 w = w1p[e4];
            a10 += u0[4*e4]*w.x + u0[4*e4+1]*w.y + u0[4*e4+2]*w.z + u0[4*e4+3]*w.w;
            a11 += u1[4*e4]*w.x + u1[4*e4+1]*w.y + u1[4*e4+2]*w.z + u1[4*e4+3]*w.w;
        }
        xm[(bb + 0) * DI + tid] = a00;
        xm[(bb + 1) * DI + tid] = a01;
        zg[(bb + 0) * DI + tid] = a10;
        zg[(bb + 1) * DI + tid] = a11;
    }
}

// ---------------------------------------------------------------------------
// K2b: grid (128, 2) = (bb-group, j-half). Phase A: conv1d+silu (gy==0 stores
// xs_g). Phase B: each thread owns j, streams the W_x row ONCE as float4 and
// computes ALL 4 rows (4 FMA/float; halves W_x L2 traffic vs R9).
// Accumulation strictly c-ascending -> bit-identical. Phase C: delta (gy==0).
// ---------------------------------------------------------------------------
__global__ __launch_bounds__(256) void k2b_conv_wx(
    const float* __restrict__ xm, const float* __restrict__ c1w,
    const float* __restrict__ conv1d_b, const float* __restrict__ W_x,
    const float* __restrict__ W_dt, const float* __restrict__ b_dt,
    float* __restrict__ xs_g, float* __restrict__ delta_g,
    float* __restrict__ Bm, float* __restrict__ Cm)
{
    const int bb = blockIdx.x * 4;
    const int gy = blockIdx.y;           // 0,1 -> j in [gy*260, gy*260+260)
    const int tid = threadIdx.x;
    __shared__ float xs_sh[4][DI];
    __shared__ float dtin[4][8];

    // phase A: conv1d + silu (recomputed per gy, stored once)
    for (int idx = tid; idx < 4 * DI; idx += 256) {
        const int r = idx >> 8, c = idx & 255;
        const int b = bb + r;
        const float4 wc = ((const float4*)c1w)[c];
        float a = conv1d_b[c];
        if (b >= 3) a += xm[(b - 3) * DI + c] * wc.x;
        if (b >= 2) a += xm[(b - 2) * DI + c] * wc.y;
        if (b >= 1) a += xm[(b - 1) * DI + c] * wc.z;
        a += xm[b * DI + c] * wc.w;
        const float s = silu_f(a);
        xs_sh[r][c] = s;
        if (gy == 0) xs_g[b * DI + c] = s;
    }
    __syncthreads();

    // phase B: one W_x row per thread, all 4 batch rows per loaded float4
    for (int jl = tid; jl < 260; jl += 256) {
        const int jj = gy * 260 + jl;                // < 520 always
        const float4* wr = (const float4*)(W_x + (size_t)jj * DI);
        const float4* x0 = (const float4*)xs_sh[0];
        const float4* x1 = (const float4*)xs_sh[1];
        const float4* x2 = (const float4*)xs_sh[2];
        const float4* x3 = (const float4*)xs_sh[3];
        float a0 = 0.0f, a1 = 0.0f, a2 = 0.0f, a3 = 0.0f;
#pragma unroll 8
        for (int c4 = 0; c4 < 64; c4++) {
            const float4 w  = wr[c4];
            const float4 v0 = x0[c4];
            const float4 v1 = x1[c4];
            const float4 v2 = x2[c4];
            const float4 v3 = x3[c4];
            a0 += v0.x*w.x; a0 += v0.y*w.y; a0 += v0.z*w.z; a0 += v0.w*w.w;
            a1 += v1.x*w.x; a1 += v1.y*w.y; a1 += v1.z*w.z; a1 += v1.w*w.w;
            a2 += v2.x*w.x; a2 += v2.y*w.y; a2 += v2.z*w.z; a2 += v2.w*w.w;
            a3 += v3.x*w.x; a3 += v3.y*w.y; a3 += v3.z*w.z; a3 += v3.w*w.w;
        }
        const float av[4] = {a0, a1, a2, a3};
        if (jj < DTR) {
#pragma unroll
            for (int r = 0; r < 4; r++) dtin[r][jj] = av[r];
        } else if (jj < DTR + S) {
#pragma unroll
            for (int r = 0; r < 4; r++) Bm[(bb + r) * S + (jj - DTR)] = av[r];
        } else {
#pragma unroll
            for (int r = 0; r < 4; r++) Cm[(bb + r) * S + (jj - DTR - S)] = av[r];
        }
    }
    __syncthreads();

    // phase C: delta = softplus(dtin @ W_dt.T + b_dt), 4 rows (gy==0 only)
    if (gy == 0) {
        const int d = tid;
        const float bd = b_dt[d];
        const float4 wd0 = ((const float4*)(W_dt + d * DTR))[0];
        const float4 wd1 = ((const float4*)(W_dt + d * DTR))[1];
#pragma unroll
        for (int r2 = 0; r2 < 4; r2++) {
            float a = bd
                + dtin[r2][0]*wd0.x + dtin[r2][1]*wd0.y + dtin[r2][2]*wd0.z + dtin[r2][3]*wd0.w
                + dtin[r2][4]*wd1.x + dtin[r2][5]*wd1.y + dtin[r2][6]*wd1.z + dtin[r2][7]*wd1.w;
            const float sp = (a > 20.0f) ? a : log1pf(__expf(a));
            delta_g[(bb + r2) * DI + d] = sp;
        }
    }
}

// ---------------------------------------------------------------------------
// K3 chunked scan (NC=32): unchanged (verified bit-identical).
// ---------------------------------------------------------------------------
__global__ __launch_bounds__(256) void k3u_up(
    const float* __restrict__ A_log, const float* __restrict__ delta,
    const float* __restrict__ xs, const float* __restrict__ Bm,
    float* __restrict__ hloc, float* __restrict__ Dchunk)
{
    const int tid = threadIdx.x;
    const int wv = tid >> 6, ln = tid & 63;
    const int d = blockIdx.x * 4 + wv;
    const int c = blockIdx.y;
    const int s0 = ln * 4;
    const int t0 = c * TCV;

    const float4 al = *(const float4*)(A_log + d * S + s0);
    float4 A;
    A.x = -__expf(al.x); A.y = -__expf(al.y);
    A.z = -__expf(al.z); A.w = -__expf(al.w);

    float4 h = make_float4(0.f, 0.f, 0.f, 0.f);
    float cd = 0.0f;
    for (int tb = 0; tb < TCV; tb += 8) {
#pragma unroll
        for (int i = 0; i < 8; i++) {
            const int tt = t0 + tb + i;
            const float dd = delta[tt * DI + d];
            cd += dd;
            const float u = dd * xs[tt * DI + d];
            const float4 B = *(const float4*)(Bm + tt * S + s0);
            h.x = __expf(dd * A.x) * h.x + u * B.x;
            h.y = __expf(dd * A.y) * h.y + u * B.y;
            h.z = __expf(dd * A.z) * h.z + u * B.z;
            h.w = __expf(dd * A.w) * h.w + u * B.w;
        }
    }
    *(float4*)(hloc + ((size_t)(c * DI + d)) * S + s0) = h;
    if (ln == 0) Dchunk[c * DI + d] = cd;
}

__global__ __launch_bounds__(256) void k3d_down(
    const float* __restrict__ A_log, const float* __restrict__ delta,
    const float* __restrict__ xs, const float* __restrict__ Bm,
    const float* __restrict__ Cm, const float* __restrict__ hloc,
    const float* __restrict__ Dchunk, float* __restrict__ y)
{
    const int tid = threadIdx.x;
    const int wv = tid >> 6, ln = tid & 63;
    const int d = blockIdx.x * 4 + wv;
    const int c = (NC - 1) - blockIdx.y;   // heavy carries first
    const int s0 = ln * 4;
    const int t0 = c * TCV;

    const float4 al = *(const float4*)(A_log + d * S + s0);
    float4 A;
    A.x = -__expf(al.x); A.y = -__expf(al.y);
    A.z = -__expf(al.z); A.w = -__expf(al.w);

    float4 h = make_float4(0.f, 0.f, 0.f, 0.f);
    for (int cp = 1; cp <= c; cp++) {
        const float4 hl = *(const float4*)(hloc + ((size_t)((cp - 1) * DI + d)) * S + s0);
        const float Dc = Dchunk[(cp - 1) * DI + d];
        h.x = hl.x + __expf(A.x * Dc) * h.x;
        h.y = hl.y + __expf(A.y * Dc) * h.y;
        h.z = hl.z + __expf(A.z * Dc) * h.z;
        h.w = hl.w + __expf(A.w * Dc) * h.w;
    }

    float pr[8];
    for (int tb = 0; tb < TCV; tb += 8) {
#pragma unroll
        for (int i = 0; i < 8; i++) {
            const int tt = t0 + tb + i;
            const float dd = delta[tt * DI + d];
            const float u = dd * xs[tt * DI + d];
            const float4 B = *(const float4*)(Bm + tt * S + s0);
            const float4 C = *(const float4*)(Cm + tt * S + s0);
            h.x = __expf(dd * A.x) * h.x + u * B.x;
            h.y = __expf(dd * A.y) * h.y + u * B.y;
            h.z = __expf(dd * A.z) * h.z + u * B.z;
            h.w = __expf(dd * A.w) * h.w + u * B.w;
            pr[i] = h.x * C.x + h.y * C.y + h.z * C.z + h.w * C.w;
        }

        float q0, q1, q2, q3;
        {
            const bool b0 = (ln & 1);
            float s_, r_;
            s_ = b0 ? pr[0] : pr[1]; r_ = __shfl_xor(s_, 1, 64);
            q0 = (b0 ? pr[1] : pr[0]) + r_;
            s_ = b0 ? pr[2] : pr[3]; r_ = __shfl_xor(s_, 1, 64);
            q1 = (b0 ? pr[3] : pr[2]) + r_;
            s_ = b0 ? pr[4] : pr[5]; r_ = __shfl_xor(s_, 1, 64);
            q2 = (b0 ? pr[5] : pr[4]) + r_;
            s_ = b0 ? pr[6] : pr[7]; r_ = __shfl_xor(s_, 1, 64);
            q3 = (b0 ? pr[7] : pr[6]) + r_;
        }
        {
            const bool b1 = (ln & 2);
            float s_, r_;
            s_ = b1 ? q0 : q1; r_ = __shfl_xor(s_, 2, 64);
            q0 = (b1 ? q1 : q0) + r_;
            s_ = b1 ? q2 : q3; r_ = __shfl_xor(s_, 2, 64);
            q1 = (b1 ? q3 : q2) + r_;
        }
        {
            const bool b2 = (ln & 4);
            const float s_ = b2 ? q0 : q1;
            const float r_ = __shfl_xor(s_, 4, 64);
            q0 = (b2 ? q1 : q0) + r_;
        }
        q0 += __shfl_xor(q0, 8, 64);
        q0 += __shfl_xor(q0, 16, 64);
        q0 += __shfl_xor(q0, 32, 64);
        if (ln < 8) y[(t0 + tb + ln) * DI + d] = q0;
    }
}

// ---------------------------------------------------------------------------
// K4: unchanged from R9.
// ---------------------------------------------------------------------------
__global__ __launch_bounds__(256) void k4_heads(
    const float* __restrict__ y, const float* __restrict__ xs,
    const float* __restrict__ Dp, const float* __restrict__ zg,
    const float* __restrict__ W_out,
    const float* __restrict__ We, const float* __restrict__ be,
    const float* __restrict__ Wa, const float* __restrict__ ba,
    const float* __restrict__ Wq, const float* __restrict__ bq,
    float* __restrict__ out)
{
    const int bb = blockIdx.x * 2;
    const int tid = threadIdx.x;
    __shared__ float yf[2][DI];
    __shared__ float feat[2][E];

    for (int idx = tid; idx < 2 * DI; idx += 256) {
        const int r = idx >> 8, c = idx & 255;
        const int b = bb + r;
        const float z = zg[b * DI + c];
        yf[r][c] = (y[b * DI + c] + xs[b * DI + c] * Dp[c]) * silu_f(z);
    }
    __syncthreads();

    {
        const int r = tid >> 7, e = tid & 127;
        const float4* wr = (const float4*)(W_out + (size_t)e * DI);
        const float4* yv = (const float4*)yf[r];
        float a = 0.0f;
#pragma unroll 8
        for (int d4 = 0; d4 < 64; d4++) {
            const float4 w = wr[d4];
            const float4 v = yv[d4];
            a += v.x * w.x; a += v.y * w.y; a += v.z * w.z; a += v.w * w.w;
        }
        feat[r][e] = a;
    }
    __syncthreads();

    if (tid < 16) {
        const int r = tid >> 3, hd = tid & 7;
        const int b = bb + r;
        const float* wrow;
        float bias;
        int dst;
        if (hd == 0)      { wrow = We;                 bias = be[0];      dst = b; }
        else if (hd < 4)  { wrow = Wa + (hd - 1) * E;  bias = ba[hd - 1]; dst = 512 + b * 3 + (hd - 1); }
        else              { wrow = Wq + (hd - 4) * E;  bias = bq[hd - 4]; dst = 2048 + b * 4 + (hd - 4); }
        float a = bias;
#pragma unroll 4
        for (int e = 0; e < E; e++) a += feat[r][e] * wrow[e];
        out[dst] = a;
    }
}

// ===========================================================================
extern "C" void kernel_launch(void* const* d_in, const int* in_sizes, int n_in,
                              void* d_out, int out_size, void* d_ws, size_t ws_size,
                              hipStream_t stream)
{
    const float* x        = (const float*)d_in[0];
    const float* conv_w   = (const float*)d_in[1];
    const float* conv_b   = (const float*)d_in[2];
    const float* lin_w    = (const float*)d_in[3];
    const float* lin_b    = (const float*)d_in[4];
    const float* W_in     = (const float*)d_in[5];
    const float* conv1d_w = (const float*)d_in[6];
    const float* conv1d_b = (const float*)d_in[7];
    const float* W_x      = (const float*)d_in[8];
    const float* W_dt     = (const float*)d_in[9];
    const float* b_dt     = (const float*)d_in[10];
    const float* A_log    = (const float*)d_in[11];
    const float* Dp       = (const float*)d_in[12];
    const float* W_out    = (const float*)d_in[13];
    const float* We       = (const float*)d_in[14];
    const float* be       = (const float*)d_in[15];
    const float* Wa       = (const float*)d_in[16];
    const float* ba       = (const float*)d_in[17];
    const float* Wq       = (const float*)d_in[18];
    const float* bq       = (const float*)d_in[19];
    float* out = (float*)d_out;

    float* ws = (float*)d_ws;
    float* xm     = ws;                    // 512*256 each below
    float* zg     = xm     + 512 * 256;
    float* xs     = zg     + 512 * 256;
    float* delta  = xs     + 512 * 256;
    float* Bm     = delta  + 512 * 256;
    float* Cm     = Bm     + 512 * 256;
    float* y      = Cm     + 512 * 256;
    float* hloc   = y      + 512 * 256;    // NC*DI*S
    float* Dchunk = hloc   + (size_t)NC * DI * S;   // NC*DI

    kA_pre<<<256, 256, 0, stream>>>(x, conv_w, conv_b, lin_w, lin_b, W_in,
                                    xm, zg);
    k2b_conv_wx<<<dim3(128, 2), 256, 0, stream>>>(xm, conv1d_w, conv1d_b, W_x,
                                                  W_dt, b_dt, xs, delta, Bm, Cm);
    k3u_up<<<dim3(64, NC), 256, 0, stream>>>(A_log, delta, xs, Bm, hloc, Dchunk);
    k3d_down<<<dim3(64, NC), 256, 0, stream>>>(A_log, delta, xs, Bm, Cm,
                                               hloc, Dchunk, y);
    k4_heads<<<256, 256, 0, stream>>>(y, xs, Dp, zg, W_out, We, be, Wa, ba, Wq, bq, out);
}